// Round 1
// baseline (119.514 us; speedup 1.0000x reference)
//
#include <hip/hip_runtime.h>

#define HID   128
#define TILE  128
#define PNUM  1024
#define NB    64
#define LASTB 63
#define BP    (NB * PNUM)   // 65536 points

// ---------------------------------------------------------------------------
// Kernel 1: fused MLP  (2 -> 128 relu -> 128 relu -> 8)
// 512 blocks x 256 threads; each block handles TILE=128 points.
// LDS: h1^T [k][p] 64KB + W2 [k][n] 64KB = 128KB (gfx950 has 160KB/CU).
// Each thread: 8 points x 8 cols register tile (cols tx*4..+3 and 64+tx*4..+3),
// then fused layer-3 partials reduced across tx lanes via shfl_xor.
// ---------------------------------------------------------------------------
__global__ __launch_bounds__(256) void mlp_kernel(
    const float* __restrict__ freqs, const float* __restrict__ mags,
    const float* __restrict__ W1, const float* __restrict__ b1,
    const float* __restrict__ W2, const float* __restrict__ b2,
    const float* __restrict__ W3, const float* __restrict__ b3,
    float* __restrict__ out)
{
    __shared__ float sA[HID * TILE];   // h1 transposed: [k][p]
    __shared__ float sB[HID * HID];    // W2: [k][n]

    const int t  = threadIdx.x;
    const int g0 = blockIdx.x * TILE;

    // ---- stage W2 into LDS (16384 floats, 16 x float4 per thread) ----
    {
        const float4* w2v = reinterpret_cast<const float4*>(W2);
        float4* sBv = reinterpret_cast<float4*>(sB);
#pragma unroll
        for (int r = 0; r < 16; ++r)
            sBv[r * 256 + t] = w2v[r * 256 + t];
    }

    // ---- layer 1: h1 = relu(f*W1[0] + m*W1[1] + b1), write transposed ----
    {
        const int p  = t & (TILE - 1);
        const int k0 = (t >> 7) * 64;           // two threads per point
        const float f = freqs[g0 + p];
        const float m = mags[g0 + p];
#pragma unroll 8
        for (int kk = 0; kk < 64; ++kk) {
            const int k = k0 + kk;
            float h = fmaf(f, W1[k], fmaf(m, W1[HID + k], b1[k]));
            sA[k * TILE + p] = fmaxf(h, 0.0f);
        }
    }
    __syncthreads();

    const int tx = t & 15;
    const int ty = t >> 4;
    const int p0 = ty * 8;     // 8 consecutive points
    const int c0 = tx * 4;     // cols c0..c0+3 and 64+c0..64+c0+3

    float acc[8][8];
#pragma unroll
    for (int i = 0; i < 8; ++i)
#pragma unroll
        for (int j = 0; j < 8; ++j) acc[i][j] = 0.0f;

    const float4* sAv = reinterpret_cast<const float4*>(sA);
    const float4* sBv = reinterpret_cast<const float4*>(sB);

    // ---- layer 2 GEMM: acc[i][j] += h1[p0+i][k] * W2[k][col_j] ----
#pragma unroll 4
    for (int k = 0; k < HID; ++k) {
        const float4 a0 = sAv[k * 32 + (p0 >> 2)];
        const float4 a1 = sAv[k * 32 + (p0 >> 2) + 1];
        const float4 bl = sBv[k * 32 + tx];        // cols c0..c0+3
        const float4 bh = sBv[k * 32 + 16 + tx];   // cols 64+c0..+3
        const float av[8] = {a0.x, a0.y, a0.z, a0.w, a1.x, a1.y, a1.z, a1.w};
        const float bv[8] = {bl.x, bl.y, bl.z, bl.w, bh.x, bh.y, bh.z, bh.w};
#pragma unroll
        for (int i = 0; i < 8; ++i)
#pragma unroll
            for (int j = 0; j < 8; ++j)
                acc[i][j] = fmaf(av[i], bv[j], acc[i][j]);
    }

    // ---- fused layer 3: partial over this thread's 8 columns ----
    float part[8][8];
#pragma unroll
    for (int i = 0; i < 8; ++i)
#pragma unroll
        for (int o = 0; o < 8; ++o) part[i][o] = 0.0f;

    const float4 b2l = reinterpret_cast<const float4*>(b2)[tx];
    const float4 b2h = reinterpret_cast<const float4*>(b2)[16 + tx];
    const float b2v[8] = {b2l.x, b2l.y, b2l.z, b2l.w, b2h.x, b2h.y, b2h.z, b2h.w};

#pragma unroll
    for (int j = 0; j < 8; ++j) {
        const int col = (j < 4) ? (c0 + j) : (64 + c0 + (j - 4));
        const float4 w3a = reinterpret_cast<const float4*>(W3)[col * 2];
        const float4 w3b = reinterpret_cast<const float4*>(W3)[col * 2 + 1];
        const float w3v[8] = {w3a.x, w3a.y, w3a.z, w3a.w, w3b.x, w3b.y, w3b.z, w3b.w};
#pragma unroll
        for (int i = 0; i < 8; ++i) {
            const float hv = fmaxf(acc[i][j] + b2v[j], 0.0f);
#pragma unroll
            for (int o = 0; o < 8; ++o)
                part[i][o] = fmaf(hv, w3v[o], part[i][o]);
        }
    }

    // ---- reduce partials across the 16 tx lanes (lane bits 0..3) ----
#pragma unroll
    for (int mk = 1; mk <= 8; mk <<= 1)
#pragma unroll
        for (int i = 0; i < 8; ++i)
#pragma unroll
            for (int o = 0; o < 8; ++o)
                part[i][o] += __shfl_xor(part[i][o], mk, 64);

    // ---- epilogue: lane tx==0 of each ty writes its 8 points ----
    if (tx == 0) {
        float b3v[8];
#pragma unroll
        for (int o = 0; o < 8; ++o) b3v[o] = b3[o];
#pragma unroll
        for (int i = 0; i < 8; ++i) {
            float4 v0 = make_float4(part[i][0] + b3v[0], part[i][1] + b3v[1],
                                    part[i][2] + b3v[2], part[i][3] + b3v[3]);
            float4 v1 = make_float4(part[i][4] + b3v[4], part[i][5] + b3v[5],
                                    part[i][6] + b3v[6], part[i][7] + b3v[7]);
            float4* op = reinterpret_cast<float4*>(out + (size_t)(g0 + p0 + i) * 8);
            op[0] = v0;
            op[1] = v1;
        }
    }
}

// ---------------------------------------------------------------------------
// Kernel 2: harmonic counts for batch LASTB only.
// 128 blocks x 256 threads; block bi covers i in [bi*8, bi*8+8), each i gets
// 32 threads each scanning 32 j's. Exact numpy-fp32 semantics via __f*_rn.
// ---------------------------------------------------------------------------
__global__ __launch_bounds__(256) void harm_count(
    const float* __restrict__ freqs, const float* __restrict__ mags,
    int* __restrict__ cnt)
{
    __shared__ float sf[PNUM];
    __shared__ float sm[PNUM];
    const float* f = freqs + (size_t)LASTB * PNUM;
    const float* m = mags  + (size_t)LASTB * PNUM;
    const int t = threadIdx.x;
#pragma unroll
    for (int r = 0; r < 4; ++r) {
        sf[t + 256 * r] = f[t + 256 * r];
        sm[t + 256 * r] = m[t + 256 * r];
    }
    __syncthreads();

    const int il = t >> 5;                  // 0..7
    const int jc = t & 31;                  // 0..31
    const int i  = blockIdx.x * 8 + il;
    const float fi = sf[i];
    float fo[7];
#pragma unroll
    for (int o = 0; o < 7; ++o) fo[o] = __fmul_rn(fi, (float)(o + 2));

    int c = 0;
    const int j0 = jc * 32;
    for (int jj = 0; jj < 32; ++jj) {
        const int j = j0 + jj;
        const float fj = sf[j];
        bool match = false;
#pragma unroll
        for (int o = 0; o < 7; ++o)
            match = match || (fabsf(__fsub_rn(fj, fo[o])) < 2.0f);
        if (match && (sm[j] > 0.0f) && (j != i)) ++c;
    }
    // reduce the 32 j-chunk partials (they sit in one 32-lane subgroup)
#pragma unroll
    for (int off = 16; off > 0; off >>= 1) c += __shfl_down(c, off, 32);
    if (jc == 0) cnt[i] = c;
}

// ---------------------------------------------------------------------------
// Kernel 3: selection. Lexicographic max over (harmonics, mag, -idx) among
// candidates; fallback argmax(mags). Keys packed into uint64.
// ---------------------------------------------------------------------------
__device__ __forceinline__ unsigned long long umax64(unsigned long long a,
                                                     unsigned long long b) {
    return a > b ? a : b;
}

__global__ __launch_bounds__(256) void harm_select(
    const float* __restrict__ freqs, const float* __restrict__ mags,
    const int* __restrict__ cnt, float* __restrict__ outF)
{
    const float* f = freqs + (size_t)LASTB * PNUM;
    const float* m = mags  + (size_t)LASTB * PNUM;
    const int t = threadIdx.x;

    unsigned long long ck = 0ull, fk = 0ull;
#pragma unroll
    for (int r = 0; r < 4; ++r) {
        const int i = t + 256 * r;
        const float mi = m[i];
        const int h = cnt[i];
        const unsigned mb = __float_as_uint(mi);
        if (mi > 0.0f && h > 0) {
            // mag > 0 => positive float bits are order-preserving (31 bits)
            const unsigned long long k =
                ((unsigned long long)h << 42) |
                ((unsigned long long)mb << 10) |
                (unsigned long long)(1023 - i);
            ck = umax64(ck, k);
        }
        // total-order encode for arbitrary-sign float
        const unsigned mo = (mb & 0x80000000u) ? ~mb : (mb | 0x80000000u);
        const unsigned long long k2 =
            ((unsigned long long)mo << 10) | (unsigned long long)(1023 - i);
        fk = umax64(fk, k2);
    }

    __shared__ unsigned long long sc[256];
    __shared__ unsigned long long sfb[256];
    sc[t] = ck;
    sfb[t] = fk;
    __syncthreads();
    for (int s = 128; s > 0; s >>= 1) {
        if (t < s) {
            sc[t]  = umax64(sc[t],  sc[t + s]);
            sfb[t] = umax64(sfb[t], sfb[t + s]);
        }
        __syncthreads();
    }
    if (t == 0) {
        const unsigned long long k = sc[0] ? sc[0] : sfb[0];
        const int idx = 1023 - (int)(k & 1023ull);
        outF[0] = f[idx];
    }
}

// ---------------------------------------------------------------------------
extern "C" void kernel_launch(void* const* d_in, const int* in_sizes, int n_in,
                              void* d_out, int out_size, void* d_ws, size_t ws_size,
                              hipStream_t stream) {
    const float* freqs = (const float*)d_in[0];
    const float* mags  = (const float*)d_in[1];
    const float* W1    = (const float*)d_in[2];
    const float* b1    = (const float*)d_in[3];
    const float* W2    = (const float*)d_in[4];
    const float* b2    = (const float*)d_in[5];
    const float* W3    = (const float*)d_in[6];
    const float* b3    = (const float*)d_in[7];
    float* out = (float*)d_out;
    int*   cnt = (int*)d_ws;

    mlp_kernel<<<BP / TILE, 256, 0, stream>>>(freqs, mags, W1, b1, W2, b2, W3, b3, out);
    harm_count<<<PNUM / 8, 256, 0, stream>>>(freqs, mags, cnt);
    harm_select<<<1, 256, 0, stream>>>(freqs, mags, cnt, out + (size_t)BP * 8);
}